// Round 1
// baseline (244.615 us; speedup 1.0000x reference)
//
#include <hip/hip_runtime.h>
#include <math.h>

#define NEGV -1e30f

// ---------------------------------------------------------------------------
// Problem geometry (fixed by reference):
//   qry   : (256, 128*128)  f32   (leading 1,1 dims dropped)
//   sup_x : (5, 256, 128*128) f32
//   sup_y : (5, 128*128) f32
//   protos M = 5*16*16 = 1280, channels C = 256, pixels HW = 16384
//   out   : (16384) f32
// pred[px] = sum_m softmax(mask? d : NEG)_m * d_m,  d = 20 * <qry_n[px], pro_n[m]>
// ---------------------------------------------------------------------------

// P0: pool sup_y 8x8 -> 1280 values, pick mask mode, write mask floats (0/1)
__global__ __launch_bounds__(256) void prep_mask_kernel(const float* __restrict__ sup_y,
                                                        float* __restrict__ maskf) {
    __shared__ float yv[1280];
    __shared__ int flags[2];
    const int t = threadIdx.x;
    if (t < 2) flags[t] = 0;
    __syncthreads();
    for (int r = 0; r < 5; ++r) {
        const int m = r * 256 + t;
        const int gy = t >> 4, gx = t & 15;
        const float* base = sup_y + r * 16384 + gy * 8 * 128 + gx * 8;
        float sum = 0.f;
#pragma unroll
        for (int rr = 0; rr < 8; ++rr) {
            const float4 a = *(const float4*)(base + rr * 128);
            const float4 b = *(const float4*)(base + rr * 128 + 4);
            sum += a.x + a.y + a.z + a.w + b.x + b.y + b.z + b.w;
        }
        const float y = sum * (1.f / 64.f);
        yv[m] = y;
        if (y > 0.5f) atomicOr(&flags[0], 1);
        if (y > 0.1f) atomicOr(&flags[1], 1);
    }
    __syncthreads();
    const int mode = flags[0] ? 0 : (flags[1] ? 1 : 2);
    for (int r = 0; r < 5; ++r) {
        const int m = r * 256 + t;
        const float y = yv[m];
        float mk;
        if (mode == 0)      mk = (y > 0.5f) ? 1.f : 0.f;
        else if (mode == 1) mk = (y > 0.1f) ? 1.f : 0.f;
        else                mk = 1.f;
        maskf[m] = mk;
    }
}

// P1: avg-pool sup_x 8x8 -> cand[m][c], m = s*256 + (gy*16+gx)
__global__ __launch_bounds__(256) void pool_kernel(const float* __restrict__ sup_x,
                                                   float* __restrict__ cand) {
    const int blk = blockIdx.x;          // s*256 + c
    const int s = blk >> 8, c = blk & 255;
    const int t = threadIdx.x;           // gy*16 + gx
    const int gy = t >> 4, gx = t & 15;
    const float* base = sup_x + (size_t)(s * 256 + c) * 16384 + gy * 8 * 128 + gx * 8;
    float sum = 0.f;
#pragma unroll
    for (int rr = 0; rr < 8; ++rr) {
        const float4 a = *(const float4*)(base + rr * 128);
        const float4 b = *(const float4*)(base + rr * 128 + 4);
        sum += a.x + a.y + a.z + a.w + b.x + b.y + b.z + b.w;
    }
    cand[(size_t)(s * 256 + t) * 256 + c] = sum * (1.f / 64.f);
}

// P2: per-proto mean-center + L2 normalize; store TRANSPOSED pro_t[c][m]
__global__ __launch_bounds__(256) void proto_kernel(const float* __restrict__ cand,
                                                    float* __restrict__ pro_t) {
    const int m = blockIdx.x;
    const int t = threadIdx.x;
    const float x = cand[(size_t)m * 256 + t];
    float s1 = x, s2 = x * x;
#pragma unroll
    for (int o = 32; o >= 1; o >>= 1) {
        s1 += __shfl_xor(s1, o, 64);
        s2 += __shfl_xor(s2, o, 64);
    }
    __shared__ float r1[4], r2[4];
    const int wv = t >> 6;
    if ((t & 63) == 0) { r1[wv] = s1; r2[wv] = s2; }
    __syncthreads();
    const float S1 = r1[0] + r1[1] + r1[2] + r1[3];
    const float S2 = r2[0] + r2[1] + r2[2] + r2[3];
    const float mu = S1 * (1.f / 256.f);
    const float nrm = sqrtf(fmaxf(S2 - 256.f * mu * mu, 0.f));
    const float inv = 1.f / fmaxf(nrm, 1e-4f);
    pro_t[(size_t)t * 1280 + m] = (x - mu) * inv;
}

// Main: per block 64 pixels x all 1280 protos, online-softmax weighted mean.
// 256 thr = 16 px-groups (4 px each) x 16 proto-groups (4 protos per tile each).
__global__ __launch_bounds__(256) void main_kernel(const float* __restrict__ qry,
                                                   const float* __restrict__ pro_t,
                                                   const float* __restrict__ maskf,
                                                   float* __restrict__ out) {
    __shared__ float qs[256 * 64];   // qs[c][px]  64 KB
    __shared__ float ps[64 * 64];    // ps[cc][mm] 16 KB (also scratch for reductions)
    __shared__ float ms[64];
    __shared__ float2 stats[64];

    const int t = threadIdx.x;
    const int px0 = blockIdx.x * 64;

    // ---- load qry tile (coalesced float4) ----
    {
        const int p4 = (t & 15) * 4;
        const int cb = t >> 4;
        for (int it = 0; it < 16; ++it) {
            const int c = cb + it * 16;
            const float4 v = *(const float4*)(qry + (size_t)c * 16384 + px0 + p4);
            *(float4*)(qs + c * 64 + p4) = v;
        }
    }
    __syncthreads();
    // ---- per-pixel mean / inv-norm ----
    {
        const int p = t & 63, qr = t >> 6;
        float s1 = 0.f, s2 = 0.f;
        for (int cc = 0; cc < 64; ++cc) {
            const float v = qs[(qr * 64 + cc) * 64 + p];
            s1 += v; s2 += v * v;
        }
        ps[qr * 64 + p] = s1;
        ps[256 + qr * 64 + p] = s2;
    }
    __syncthreads();
    if (t < 64) {
        const int p = t;
        float S1 = 0.f, S2 = 0.f;
        for (int q = 0; q < 4; ++q) { S1 += ps[q * 64 + p]; S2 += ps[256 + q * 64 + p]; }
        const float mu = S1 * (1.f / 256.f);
        const float nrm = sqrtf(fmaxf(S2 - 256.f * mu * mu, 0.f));
        const float inv = 1.f / fmaxf(nrm, 1e-4f);
        stats[p] = make_float2(mu, inv);
    }
    __syncthreads();
    // ---- normalize in LDS ----
    {
        const int p = t & 63, qr = t >> 6;
        const float2 st = stats[p];
        for (int cc = 0; cc < 64; ++cc) {
            const int idx = (qr * 64 + cc) * 64 + p;
            qs[idx] = (qs[idx] - st.x) * st.y;
        }
    }

    const int i = t & 15;   // pixel group: px 4i..4i+3
    const int j = t >> 4;   // proto group: m m0+4j..4j+3
    float acc[4][4];
    float Mst[4], Sa[4], Wa[4];
#pragma unroll
    for (int pi = 0; pi < 4; ++pi) {
        Mst[pi] = NEGV; Sa[pi] = 0.f; Wa[pi] = 0.f;
#pragma unroll
        for (int pj = 0; pj < 4; ++pj) acc[pi][pj] = 0.f;
    }

    for (int tile = 0; tile < 20; ++tile) {
        const int m0 = tile * 64;
        for (int kc = 0; kc < 4; ++kc) {
            __syncthreads();
            {   // stage 64c x 64m proto chunk (coalesced: mm contiguous)
                const int mm = t & 63, ccb = t >> 6;
                for (int it = 0; it < 16; ++it) {
                    const int cc = it * 4 + ccb;
                    ps[cc * 64 + mm] = pro_t[(size_t)(kc * 64 + cc) * 1280 + m0 + mm];
                }
                if (kc == 0 && t < 64) ms[t] = maskf[m0 + t];
            }
            __syncthreads();
            const float* qbase = qs + (kc * 64) * 64 + 4 * i;
            const float* pbase = ps + 4 * j;
#pragma unroll 8
            for (int cc = 0; cc < 64; ++cc) {
                const float4 q = *(const float4*)(qbase + cc * 64);
                const float4 p = *(const float4*)(pbase + cc * 64);
                acc[0][0] += q.x * p.x; acc[0][1] += q.x * p.y; acc[0][2] += q.x * p.z; acc[0][3] += q.x * p.w;
                acc[1][0] += q.y * p.x; acc[1][1] += q.y * p.y; acc[1][2] += q.y * p.z; acc[1][3] += q.y * p.w;
                acc[2][0] += q.z * p.x; acc[2][1] += q.z * p.y; acc[2][2] += q.z * p.z; acc[2][3] += q.z * p.w;
                acc[3][0] += q.w * p.x; acc[3][1] += q.w * p.y; acc[3][2] += q.w * p.z; acc[3][3] += q.w * p.w;
            }
        }
        // ---- online softmax update (per pixel, over this tile's 4 protos) ----
        float mk[4];
#pragma unroll
        for (int pj = 0; pj < 4; ++pj) mk[pj] = ms[j * 4 + pj];
#pragma unroll
        for (int pi = 0; pi < 4; ++pi) {
            float dm[4];
#pragma unroll
            for (int pj = 0; pj < 4; ++pj) {
                const float d = 20.f * acc[pi][pj];
                dm[pj] = (mk[pj] > 0.5f) ? d : NEGV;
                acc[pi][pj] = 0.f;
            }
            const float mx = fmaxf(fmaxf(dm[0], dm[1]), fmaxf(dm[2], dm[3]));
            const float Mn = fmaxf(Mst[pi], mx);
            const float sc = __expf(Mst[pi] - Mn);   // NEGV-NEGV=0 -> 1, S/W are 0: safe
            float ssum = 0.f, wsum = 0.f;
#pragma unroll
            for (int pj = 0; pj < 4; ++pj) {
                const float e = mk[pj] * __expf(dm[pj] - Mn);  // gated: masked -> exactly 0
                ssum += e; wsum += e * dm[pj];
            }
            Mst[pi] = Mn;
            Sa[pi] = Sa[pi] * sc + ssum;
            Wa[pi] = Wa[pi] * sc + wsum;
        }
    }

    __syncthreads();
    // ---- merge the 16 proto-groups per pixel ----
    {
        float* Mr = ps; float* Sr = ps + 1024; float* Wr = ps + 2048;
#pragma unroll
        for (int pi = 0; pi < 4; ++pi) {
            const int px = 4 * i + pi;
            Mr[j * 64 + px] = Mst[pi];
            Sr[j * 64 + px] = Sa[pi];
            Wr[j * 64 + px] = Wa[pi];
        }
    }
    __syncthreads();
    if (t < 64) {
        const int px = t;
        const float* Mr = ps; const float* Sr = ps + 1024; const float* Wr = ps + 2048;
        float Mt = NEGV, St = 0.f, Wt = 0.f;
        for (int jj = 0; jj < 16; ++jj) {
            const float m_ = Mr[jj * 64 + px];
            const float s_ = Sr[jj * 64 + px];
            const float w_ = Wr[jj * 64 + px];
            const float Mn = fmaxf(Mt, m_);
            const float sc1 = __expf(Mt - Mn);
            const float sc2 = __expf(m_ - Mn);
            St = St * sc1 + s_ * sc2;
            Wt = Wt * sc1 + w_ * sc2;
            Mt = Mn;
        }
        out[px0 + px] = Wt / St;
    }
}

extern "C" void kernel_launch(void* const* d_in, const int* in_sizes, int n_in,
                              void* d_out, int out_size, void* d_ws, size_t ws_size,
                              hipStream_t stream) {
    const float* qry   = (const float*)d_in[0];   // 256*16384
    const float* sup_x = (const float*)d_in[1];   // 5*256*16384
    const float* sup_y = (const float*)d_in[2];   // 5*16384
    float* out = (float*)d_out;                   // 16384

    float* cand  = (float*)d_ws;                  // 1280*256
    float* pro_t = cand + 1280 * 256;             // 256*1280
    float* maskf = pro_t + 256 * 1280;            // 1280

    prep_mask_kernel<<<1, 256, 0, stream>>>(sup_y, maskf);
    pool_kernel<<<1280, 256, 0, stream>>>(sup_x, cand);
    proto_kernel<<<1280, 256, 0, stream>>>(cand, pro_t);
    main_kernel<<<256, 256, 0, stream>>>(qry, pro_t, maskf, out);
}

// Round 2
// 70.889 us; speedup vs baseline: 3.4507x; 3.4507x over previous
//
#include <hip/hip_runtime.h>
#include <math.h>

#define NEGV -1e30f

typedef _Float16 f16x8 __attribute__((ext_vector_type(8)));
typedef float f32x4 __attribute__((ext_vector_type(4)));

// ---------------------------------------------------------------------------
// Geometry: qry (256c, 16384px) f32; sup_x (5,256,16384) f32; sup_y (5,16384)
// protos M=1280, C=256, PX=16384. out (16384) f32.
// pred[px] = sum_m softmax(mask? d : NEG)_m * d_m, d = 20*<qry_n[px],pro_n[m]>
// f16 layouts are PRE-SWIZZLED in global: row r (px or m), 16B chunk g stored
// at chunk position g ^ (r&7)  ->  main kernel stages with linear
// global_load_lds and reads fragments with the same XOR.
// ---------------------------------------------------------------------------

__global__ __launch_bounds__(256) void prep_mask_kernel(const float* __restrict__ sup_y,
                                                        float* __restrict__ maskf) {
    __shared__ float yv[1280];
    __shared__ int flags[2];
    const int t = threadIdx.x;
    if (t < 2) flags[t] = 0;
    __syncthreads();
    for (int r = 0; r < 5; ++r) {
        const int gy = t >> 4, gx = t & 15;
        const float* base = sup_y + r * 16384 + gy * 8 * 128 + gx * 8;
        float sum = 0.f;
#pragma unroll
        for (int rr = 0; rr < 8; ++rr) {
            const float4 a = *(const float4*)(base + rr * 128);
            const float4 b = *(const float4*)(base + rr * 128 + 4);
            sum += a.x + a.y + a.z + a.w + b.x + b.y + b.z + b.w;
        }
        const float y = sum * (1.f / 64.f);
        yv[r * 256 + t] = y;
        if (y > 0.5f) atomicOr(&flags[0], 1);
        if (y > 0.1f) atomicOr(&flags[1], 1);
    }
    __syncthreads();
    const int mode = flags[0] ? 0 : (flags[1] ? 1 : 2);
    for (int r = 0; r < 5; ++r) {
        const float y = yv[r * 256 + t];
        float mk;
        if (mode == 0)      mk = (y > 0.5f) ? 1.f : 0.f;
        else if (mode == 1) mk = (y > 0.1f) ? 1.f : 0.f;
        else                mk = 1.f;
        maskf[r * 256 + t] = mk;
    }
}

__global__ __launch_bounds__(256) void pool_kernel(const float* __restrict__ sup_x,
                                                   float* __restrict__ cand) {
    const int blk = blockIdx.x;          // s*256 + c
    const int s = blk >> 8, c = blk & 255;
    const int t = threadIdx.x;           // gy*16 + gx
    const int gy = t >> 4, gx = t & 15;
    const float* base = sup_x + (size_t)(s * 256 + c) * 16384 + gy * 8 * 128 + gx * 8;
    float sum = 0.f;
#pragma unroll
    for (int rr = 0; rr < 8; ++rr) {
        const float4 a = *(const float4*)(base + rr * 128);
        const float4 b = *(const float4*)(base + rr * 128 + 4);
        sum += a.x + a.y + a.z + a.w + b.x + b.y + b.z + b.w;
    }
    cand[(size_t)(s * 256 + t) * 256 + c] = sum * (1.f / 64.f);
}

// per-proto mean-center + L2-normalize -> f16, pre-swizzled row-major [m][256]
__global__ __launch_bounds__(256) void proto_fin_kernel(const float* __restrict__ cand,
                                                        _Float16* __restrict__ pro_hs) {
    const int m = blockIdx.x;
    const int t = threadIdx.x;
    const float x = cand[(size_t)m * 256 + t];
    float s1 = x, s2 = x * x;
#pragma unroll
    for (int o = 32; o >= 1; o >>= 1) {
        s1 += __shfl_xor(s1, o, 64);
        s2 += __shfl_xor(s2, o, 64);
    }
    __shared__ float r1[4], r2[4];
    __shared__ float prow[256];
    const int wv = t >> 6;
    if ((t & 63) == 0) { r1[wv] = s1; r2[wv] = s2; }
    __syncthreads();
    const float S1 = r1[0] + r1[1] + r1[2] + r1[3];
    const float S2 = r2[0] + r2[1] + r2[2] + r2[3];
    const float mu = S1 * (1.f / 256.f);
    const float nrm = sqrtf(fmaxf(S2 - 256.f * mu * mu, 0.f));
    const float inv = 1.f / fmaxf(nrm, 1e-4f);
    prow[t] = (x - mu) * inv;
    __syncthreads();
    if (t < 32) {
        const int g = t;
        f16x8 hv;
#pragma unroll
        for (int j = 0; j < 8; ++j) hv[j] = (_Float16)prow[g * 8 + j];
        *(f16x8*)(pro_hs + (size_t)m * 256 + ((g ^ (m & 7)) << 3)) = hv;
    }
}

// per-pixel mean-center + L2-normalize of qry -> f16, pre-swizzled [px][256]
__global__ __launch_bounds__(256) void qnorm_kernel(const float* __restrict__ qry,
                                                    _Float16* __restrict__ qn_hs) {
    __shared__ float qt[256 * 65];    // [c][px] padded (+1 word) : conflict-light
    __shared__ float rs[512];
    __shared__ float2 stats[64];
    const int t = threadIdx.x;
    const int px0 = blockIdx.x * 64;
    for (int it = 0; it < 16; ++it) {
        const int c = (t >> 4) + it * 16;
        const float4 v = *(const float4*)(qry + (size_t)c * 16384 + px0 + (t & 15) * 4);
        float* dst = qt + c * 65 + (t & 15) * 4;
        dst[0] = v.x; dst[1] = v.y; dst[2] = v.z; dst[3] = v.w;
    }
    __syncthreads();
    {
        const int p = t & 63, q = t >> 6;
        float s1 = 0.f, s2 = 0.f;
        for (int cc = 0; cc < 64; ++cc) {
            const float x = qt[(q * 64 + cc) * 65 + p];
            s1 += x; s2 += x * x;
        }
        rs[q * 64 + p] = s1;
        rs[256 + q * 64 + p] = s2;
    }
    __syncthreads();
    if (t < 64) {
        float S1 = 0.f, S2 = 0.f;
        for (int q = 0; q < 4; ++q) { S1 += rs[q * 64 + t]; S2 += rs[256 + q * 64 + t]; }
        const float mu = S1 * (1.f / 256.f);
        const float nrm = sqrtf(fmaxf(S2 - 256.f * mu * mu, 0.f));
        const float inv = 1.f / fmaxf(nrm, 1e-4f);
        stats[t] = make_float2(mu, inv);
    }
    __syncthreads();
    {
        const int px = t >> 2, cq = t & 3;
        const float2 st = stats[px];
        for (int u = 0; u < 8; ++u) {
            const int g = cq * 8 + u;
            f16x8 hv;
#pragma unroll
            for (int j = 0; j < 8; ++j)
                hv[j] = (_Float16)((qt[(g * 8 + j) * 65 + px] - st.x) * st.y);
            *(f16x8*)(qn_hs + (size_t)(px0 + px) * 256 + ((g ^ (px & 7)) << 3)) = hv;
        }
    }
}

__device__ __forceinline__ void gload_lds16(const _Float16* g, _Float16* l) {
    __builtin_amdgcn_global_load_lds((const __attribute__((address_space(1))) unsigned int*)g,
                                     (__attribute__((address_space(3))) unsigned int*)l,
                                     16, 0, 0);
}

// Main: 256 blocks x 512 thr. Block: 64 px, loop over 20 proto-tiles of 64 m.
// Wave w: px-half h=w&1 (32 px as 2 MFMA cols tiles), m-slice v=w>>1 (16 m).
__global__ __launch_bounds__(512, 1) void main_kernel(const _Float16* __restrict__ qn_hs,
                                                      const _Float16* __restrict__ pro_hs,
                                                      const float* __restrict__ maskf,
                                                      float* __restrict__ out) {
    __shared__ __align__(16) _Float16 qs[64 * 256];   // 32 KB, swizzled rows [px]
    __shared__ __align__(16) _Float16 ps[64 * 256];   // 32 KB, swizzled rows [m]
    __shared__ float red[64 * 16 * 3];                // 12 KB merge buffer

    const int t = threadIdx.x;
    const int w = t >> 6, l = t & 63;
    const int h = w & 1;          // px half
    const int v = w >> 1;         // m 16-slice (0..3)
    const int ln = l & 15, lq = l >> 4;
    const int px0 = blockIdx.x * 64;

    // stage qry tile (linear copy; data pre-swizzled in global)
#pragma unroll
    for (int i = 0; i < 4; ++i) {
        const int off = w * 2048 + i * 512;
        gload_lds16(qn_hs + (size_t)px0 * 256 + off + l * 8, qs + off);
    }

    const int arow = v * 16 + ln;        // ps row for A frag (m within tile)
    const int pxA = h * 32 + ln;         // qs row for B frag, pxt=0
    const int pxB = pxA + 16;            // pxt=1  (same &7 -> same swizzle)
    const int sA = arow & 7, sB = pxA & 7;

    float Mst[2] = {NEGV, NEGV}, Sa[2] = {0.f, 0.f}, Wa[2] = {0.f, 0.f};

    for (int tile = 0; tile < 20; ++tile) {
        const int m0 = tile * 64;
        __syncthreads();   // all waves done reading previous ps
#pragma unroll
        for (int i = 0; i < 4; ++i) {
            const int off = w * 2048 + i * 512;
            gload_lds16(pro_hs + (size_t)m0 * 256 + off + l * 8, ps + off);
        }
        float mk[4];
#pragma unroll
        for (int r = 0; r < 4; ++r) mk[r] = maskf[m0 + v * 16 + lq * 4 + r];
        __syncthreads();   // drains vmcnt -> ps (and qs on first iter) ready

        f32x4 acc0 = {0.f, 0.f, 0.f, 0.f}, acc1 = {0.f, 0.f, 0.f, 0.f};
#pragma unroll
        for (int ks = 0; ks < 8; ++ks) {
            const int g = ks * 4 + lq;
            const f16x8 a  = *(const f16x8*)(ps + arow * 256 + ((g ^ sA) << 3));
            const f16x8 b0 = *(const f16x8*)(qs + pxA * 256 + ((g ^ sB) << 3));
            const f16x8 b1 = *(const f16x8*)(qs + pxB * 256 + ((g ^ sB) << 3));
            acc0 = __builtin_amdgcn_mfma_f32_16x16x32_f16(a, b0, acc0, 0, 0, 0);
            acc1 = __builtin_amdgcn_mfma_f32_16x16x32_f16(a, b1, acc1, 0, 0, 0);
        }

        // online softmax update: lane owns 4 m's (rows lq*4+r) for px cols
#pragma unroll
        for (int pxt = 0; pxt < 2; ++pxt) {
            const f32x4 A = pxt ? acc1 : acc0;
            float dm[4];
#pragma unroll
            for (int r = 0; r < 4; ++r) {
                const float d = 20.f * A[r];
                dm[r] = (mk[r] > 0.5f) ? d : NEGV;
            }
            const float mx = fmaxf(fmaxf(dm[0], dm[1]), fmaxf(dm[2], dm[3]));
            const float Mn = fmaxf(Mst[pxt], mx);
            const float sc = __expf(Mst[pxt] - Mn);
            float ssum = 0.f, wsum = 0.f;
#pragma unroll
            for (int r = 0; r < 4; ++r) {
                const float e = mk[r] * __expf(dm[r] - Mn);
                ssum += e; wsum += e * dm[r];
            }
            Mst[pxt] = Mn;
            Sa[pxt] = Sa[pxt] * sc + ssum;
            Wa[pxt] = Wa[pxt] * sc + wsum;
        }
    }

    __syncthreads();
#pragma unroll
    for (int pxt = 0; pxt < 2; ++pxt) {
        const int px = h * 32 + pxt * 16 + ln;
        const int slot = v * 4 + lq;
        float* rp = red + (px * 16 + slot) * 3;
        rp[0] = Mst[pxt]; rp[1] = Sa[pxt]; rp[2] = Wa[pxt];
    }
    __syncthreads();
    if (t < 64) {
        float Mt = NEGV, St = 0.f, Wt = 0.f;
        for (int s = 0; s < 16; ++s) {
            const float* rp = red + (t * 16 + s) * 3;
            const float m_ = rp[0], s_ = rp[1], w_ = rp[2];
            const float Mn = fmaxf(Mt, m_);
            const float sc1 = __expf(Mt - Mn);
            const float sc2 = __expf(m_ - Mn);
            St = St * sc1 + s_ * sc2;
            Wt = Wt * sc1 + w_ * sc2;
            Mt = Mn;
        }
        out[px0 + t] = Wt / St;
    }
}

extern "C" void kernel_launch(void* const* d_in, const int* in_sizes, int n_in,
                              void* d_out, int out_size, void* d_ws, size_t ws_size,
                              hipStream_t stream) {
    const float* qry   = (const float*)d_in[0];   // 256*16384
    const float* sup_x = (const float*)d_in[1];   // 5*256*16384
    const float* sup_y = (const float*)d_in[2];   // 5*16384
    float* out = (float*)d_out;                   // 16384

    char* ws = (char*)d_ws;
    float*     cand   = (float*)ws;                          ws += 1280 * 256 * 4;   // 1.25 MB
    float*     maskf  = (float*)ws;                          ws += 1280 * 4;
    _Float16*  pro_hs = (_Float16*)ws;                       ws += 1280 * 256 * 2;   // 640 KB
    _Float16*  qn_hs  = (_Float16*)ws;                       /* 16384*256*2 = 8 MB */

    prep_mask_kernel<<<1, 256, 0, stream>>>(sup_y, maskf);
    pool_kernel<<<1280, 256, 0, stream>>>(sup_x, cand);
    proto_fin_kernel<<<1280, 256, 0, stream>>>(cand, pro_hs);
    qnorm_kernel<<<256, 256, 0, stream>>>(qry, qn_hs);
    main_kernel<<<256, 512, 0, stream>>>(qn_hs, pro_hs, maskf, out);
}

// Round 3
// 60.453 us; speedup vs baseline: 4.0464x; 1.1726x over previous
//
#include <hip/hip_runtime.h>
#include <math.h>

typedef _Float16 f16x8 __attribute__((ext_vector_type(8)));
typedef float f32x4 __attribute__((ext_vector_type(4)));

// ---------------------------------------------------------------------------
// Geometry: qry (256c, 16384px) f32; sup_x (5,256,16384) f32; sup_y (5,16384)
// protos M=1280, C=256, PX=16384. out (16384) f32.
// pred[px] = sum_m softmax(mask? d : NEG)_m * d_m, d = 20*<qry_n[px],pro_n[m]>
// Since d <= 20 always, softmax uses FIXED max 20: e = mk*exp(d-20) >= e^-40.
// f16 proto layout PRE-SWIZZLED in global: row m, 16B chunk g stored at
// chunk g ^ (m&7) -> main stages with linear global_load_lds, reads with XOR.
// ---------------------------------------------------------------------------

// K1: blocks 0..1279 avg-pool sup_x -> cand[m][c]; block 1280 builds maskf.
__global__ __launch_bounds__(256) void prep_kernel(const float* __restrict__ sup_x,
                                                   const float* __restrict__ sup_y,
                                                   float* __restrict__ cand,
                                                   float* __restrict__ maskf) {
    __shared__ float yv[1280];
    __shared__ int flags[2];
    const int b = blockIdx.x;
    const int t = threadIdx.x;
    if (b < 1280) {
        const int s = b >> 8, c = b & 255;
        const int gy = t >> 4, gx = t & 15;
        const float* base = sup_x + (size_t)(s * 256 + c) * 16384 + gy * 8 * 128 + gx * 8;
        float sum = 0.f;
#pragma unroll
        for (int rr = 0; rr < 8; ++rr) {
            const float4 a = *(const float4*)(base + rr * 128);
            const float4 bb = *(const float4*)(base + rr * 128 + 4);
            sum += a.x + a.y + a.z + a.w + bb.x + bb.y + bb.z + bb.w;
        }
        cand[(size_t)(s * 256 + t) * 256 + c] = sum * (1.f / 64.f);
    } else {
        if (t < 2) flags[t] = 0;
        __syncthreads();
        for (int r = 0; r < 5; ++r) {
            const int gy = t >> 4, gx = t & 15;
            const float* base = sup_y + r * 16384 + gy * 8 * 128 + gx * 8;
            float sum = 0.f;
#pragma unroll
            for (int rr = 0; rr < 8; ++rr) {
                const float4 a = *(const float4*)(base + rr * 128);
                const float4 bb = *(const float4*)(base + rr * 128 + 4);
                sum += a.x + a.y + a.z + a.w + bb.x + bb.y + bb.z + bb.w;
            }
            const float y = sum * (1.f / 64.f);
            yv[r * 256 + t] = y;
            if (y > 0.5f) atomicOr(&flags[0], 1);
            if (y > 0.1f) atomicOr(&flags[1], 1);
        }
        __syncthreads();
        const int mode = flags[0] ? 0 : (flags[1] ? 1 : 2);
        for (int r = 0; r < 5; ++r) {
            const float y = yv[r * 256 + t];
            float mk;
            if (mode == 0)      mk = (y > 0.5f) ? 1.f : 0.f;
            else if (mode == 1) mk = (y > 0.1f) ? 1.f : 0.f;
            else                mk = 1.f;
            maskf[r * 256 + t] = mk;
        }
    }
}

// K2: per-proto mean-center + L2-normalize -> f16, pre-swizzled [m][256]
__global__ __launch_bounds__(256) void proto_fin_kernel(const float* __restrict__ cand,
                                                        _Float16* __restrict__ pro_hs) {
    const int m = blockIdx.x;
    const int t = threadIdx.x;
    const float x = cand[(size_t)m * 256 + t];
    float s1 = x, s2 = x * x;
#pragma unroll
    for (int o = 32; o >= 1; o >>= 1) {
        s1 += __shfl_xor(s1, o, 64);
        s2 += __shfl_xor(s2, o, 64);
    }
    __shared__ float r1[4], r2[4];
    __shared__ float prow[256];
    const int wv = t >> 6;
    if ((t & 63) == 0) { r1[wv] = s1; r2[wv] = s2; }
    __syncthreads();
    const float S1 = r1[0] + r1[1] + r1[2] + r1[3];
    const float S2 = r2[0] + r2[1] + r2[2] + r2[3];
    const float mu = S1 * (1.f / 256.f);
    const float nrm = sqrtf(fmaxf(S2 - 256.f * mu * mu, 0.f));
    const float inv = 1.f / fmaxf(nrm, 1e-4f);
    prow[t] = (x - mu) * inv;
    __syncthreads();
    if (t < 32) {
        const int g = t;
        f16x8 hv;
#pragma unroll
        for (int j = 0; j < 8; ++j) hv[j] = (_Float16)prow[g * 8 + j];
        *(f16x8*)(pro_hs + (size_t)m * 256 + ((g ^ (m & 7)) << 3)) = hv;
    }
}

__device__ __forceinline__ void gload_lds16(const _Float16* g, _Float16* l) {
    __builtin_amdgcn_global_load_lds((const __attribute__((address_space(1))) unsigned int*)g,
                                     (__attribute__((address_space(3))) unsigned int*)l,
                                     16, 0, 0);
}

// K3: 256 blocks x 512 thr. Block: 64 px. Prologue: load+normalize qry -> qs
// (f16, XOR-swizzled). Loop 20 proto-tiles of 64 m, double-buffered staging.
// Wave w: px-half h=w&1, m 16-slice v=w>>1. Fixed-max-20 softmax accumulation.
__global__ __launch_bounds__(512, 1) void main_kernel(const float* __restrict__ qry,
                                                      const _Float16* __restrict__ pro_hs,
                                                      const float* __restrict__ maskf,
                                                      float* __restrict__ out) {
    __shared__ __align__(16) _Float16 qs[64 * 256];      // 32 KB swizzled qry f16
    __shared__ __align__(16) _Float16 ps[2][64 * 256];   // 64 KB proto dbuf (f32 qt in prologue)
    __shared__ float red[2048];                          // 8 KB scratch / merge
    __shared__ float2 stats[64];
    __shared__ float ms[1280];                           // 5 KB masks

    const int t = threadIdx.x;
    const int w = t >> 6, l = t & 63;
    const int px0 = blockIdx.x * 64;
    float* qtf = (float*)ps;                             // [c][64px] f32 staging

    // ---- prologue: load qry tile + masks ----
    {
        const int pq = (t & 15) * 4, cb = t >> 4;        // cb 0..31
#pragma unroll
        for (int it = 0; it < 8; ++it) {
            const int c = cb + it * 32;
            const float4 v = *(const float4*)(qry + (size_t)c * 16384 + px0 + pq);
            *(float4*)(qtf + c * 64 + pq) = v;
        }
#pragma unroll
        for (int it = 0; it < 3; ++it) {
            const int idx = it * 512 + t;
            if (idx < 1280) ms[idx] = maskf[idx];
        }
    }
    __syncthreads();
    {   // per-px partial sums over 32 channels each
        const int p = t & 63, q = t >> 6;
        float s1 = 0.f, s2 = 0.f;
        for (int cc = 0; cc < 32; ++cc) {
            const float x = qtf[(q * 32 + cc) * 64 + p];
            s1 += x; s2 += x * x;
        }
        red[q * 64 + p] = s1;
        red[512 + q * 64 + p] = s2;
    }
    __syncthreads();
    if (t < 64) {
        float S1 = 0.f, S2 = 0.f;
        for (int q = 0; q < 8; ++q) { S1 += red[q * 64 + t]; S2 += red[512 + q * 64 + t]; }
        const float mu = S1 * (1.f / 256.f);
        const float nrm = sqrtf(fmaxf(S2 - 256.f * mu * mu, 0.f));
        stats[t] = make_float2(mu, 1.f / fmaxf(nrm, 1e-4f));
    }
    __syncthreads();
    {   // normalize -> qs f16 swizzled
        const int px = t >> 3, cq = t & 7;
        const float2 st = stats[px];
#pragma unroll
        for (int u = 0; u < 4; ++u) {
            const int g = cq * 4 + u;
            f16x8 hv;
#pragma unroll
            for (int j = 0; j < 8; ++j)
                hv[j] = (_Float16)((qtf[(g * 8 + j) * 64 + px] - st.x) * st.y);
            *(f16x8*)(qs + px * 256 + ((g ^ (px & 7)) << 3)) = hv;
        }
    }
    __syncthreads();   // qt reads done -> ps region free for proto staging

    // ---- stage tile 0 ----
#pragma unroll
    for (int i = 0; i < 4; ++i) {
        const int off = w * 2048 + i * 512;
        gload_lds16(pro_hs + off + l * 8, ps[0] + off);
    }

    const int ln = l & 15, lq = l >> 4;
    const int h = w & 1, v = w >> 1;
    const int arow = v * 16 + ln;
    const int pxA = h * 32 + ln, pxB = pxA + 16;
    const int sA = arow & 7, sB = pxA & 7;

    float Sa[2] = {0.f, 0.f}, Wa[2] = {0.f, 0.f};

    for (int tile = 0; tile < 20; ++tile) {
        __syncthreads();                 // drains vmcnt -> ps[cur] ready
        const int cur = tile & 1;
        if (tile < 19) {                 // prefetch next tile into other buffer
            const size_t gb = (size_t)(tile + 1) * 64 * 256;
#pragma unroll
            for (int i = 0; i < 4; ++i) {
                const int off = w * 2048 + i * 512;
                gload_lds16(pro_hs + gb + off + l * 8, ps[cur ^ 1] + off);
            }
        }
        const f32x4 mkv = *(const f32x4*)(ms + tile * 64 + v * 16 + lq * 4);
        const _Float16* pb = ps[cur];

        f32x4 acc0 = {0.f, 0.f, 0.f, 0.f}, acc1 = {0.f, 0.f, 0.f, 0.f};
#pragma unroll
        for (int ks = 0; ks < 8; ++ks) {
            const int g = ks * 4 + lq;
            const f16x8 a  = *(const f16x8*)(pb + arow * 256 + ((g ^ sA) << 3));
            const f16x8 b0 = *(const f16x8*)(qs + pxA * 256 + ((g ^ sB) << 3));
            const f16x8 b1 = *(const f16x8*)(qs + pxB * 256 + ((g ^ sB) << 3));
            acc0 = __builtin_amdgcn_mfma_f32_16x16x32_f16(a, b0, acc0, 0, 0, 0);
            acc1 = __builtin_amdgcn_mfma_f32_16x16x32_f16(a, b1, acc1, 0, 0, 0);
        }

        // fixed-max epilogue: e = mk * exp(d - 20), S += e, W += e*d
#pragma unroll
        for (int pxt = 0; pxt < 2; ++pxt) {
            const f32x4 A = pxt ? acc1 : acc0;
            float ssum = 0.f, wsum = 0.f;
#pragma unroll
            for (int r = 0; r < 4; ++r) {
                const float d = 20.f * A[r];
                const float e = mkv[r] * __expf(d - 20.f);
                ssum += e; wsum += e * d;
            }
            Sa[pxt] += ssum; Wa[pxt] += wsum;
        }
    }

    __syncthreads();
#pragma unroll
    for (int pxt = 0; pxt < 2; ++pxt) {
        const int px = h * 32 + pxt * 16 + ln;
        const int slot = v * 4 + lq;
        red[px * 16 + slot] = Sa[pxt];
        red[1024 + px * 16 + slot] = Wa[pxt];
    }
    __syncthreads();
    if (t < 64) {
        float S = 0.f, W = 0.f;
        for (int s = 0; s < 16; ++s) { S += red[t * 16 + s]; W += red[1024 + t * 16 + s]; }
        out[px0 + t] = W / S;
    }
}

extern "C" void kernel_launch(void* const* d_in, const int* in_sizes, int n_in,
                              void* d_out, int out_size, void* d_ws, size_t ws_size,
                              hipStream_t stream) {
    const float* qry   = (const float*)d_in[0];   // 256*16384
    const float* sup_x = (const float*)d_in[1];   // 5*256*16384
    const float* sup_y = (const float*)d_in[2];   // 5*16384
    float* out = (float*)d_out;                   // 16384

    char* ws = (char*)d_ws;
    float*     cand   = (float*)ws;               ws += 1280 * 256 * 4;   // 1.25 MB
    float*     maskf  = (float*)ws;               ws += 1280 * 4;
    _Float16*  pro_hs = (_Float16*)ws;            /* 640 KB */

    prep_kernel<<<1281, 256, 0, stream>>>(sup_x, sup_y, cand, maskf);
    proto_fin_kernel<<<1280, 256, 0, stream>>>(cand, pro_hs);
    main_kernel<<<256, 512, 0, stream>>>(qry, pro_hs, maskf, out);
}

// Round 4
// 52.425 us; speedup vs baseline: 4.6660x; 1.1531x over previous
//
#include <hip/hip_runtime.h>
#include <math.h>

typedef _Float16 f16x8 __attribute__((ext_vector_type(8)));
typedef float f32x4 __attribute__((ext_vector_type(4)));

// ---------------------------------------------------------------------------
// Geometry: qry (256c, 16384px) f32; sup_x (5,256,16384) f32; sup_y (5,16384)
// protos M=1280, C=256, PX=16384. out (16384) f32.
// pred[px] = sum_m softmax(mask? d : NEG)_m * d_m, d = 20*<qry_n[px],pro_n[m]>
// d <= 20 always -> FIXED-max softmax: e = mk*exp(d-20) >= e^-40 (no under/ovf).
// f16 proto layout PRE-SWIZZLED in global: row m, 16B chunk g stored at
// chunk g ^ (m&7) -> main stages with linear global_load_lds, reads with XOR.
// ---------------------------------------------------------------------------

// K1: blocks 0..1279 avg-pool sup_x -> cand[m][c]; block 1280 builds maskf.
__global__ __launch_bounds__(256) void prep_kernel(const float* __restrict__ sup_x,
                                                   const float* __restrict__ sup_y,
                                                   float* __restrict__ cand,
                                                   float* __restrict__ maskf) {
    __shared__ float yv[1280];
    __shared__ int flags[2];
    const int b = blockIdx.x;
    const int t = threadIdx.x;
    if (b < 1280) {
        const int s = b >> 8, c = b & 255;
        const int gy = t >> 4, gx = t & 15;
        const float* base = sup_x + (size_t)(s * 256 + c) * 16384 + gy * 8 * 128 + gx * 8;
        float sum = 0.f;
#pragma unroll
        for (int rr = 0; rr < 8; ++rr) {
            const float4 a = *(const float4*)(base + rr * 128);
            const float4 bb = *(const float4*)(base + rr * 128 + 4);
            sum += a.x + a.y + a.z + a.w + bb.x + bb.y + bb.z + bb.w;
        }
        cand[(size_t)(s * 256 + t) * 256 + c] = sum * (1.f / 64.f);
    } else {
        if (t < 2) flags[t] = 0;
        __syncthreads();
        for (int r = 0; r < 5; ++r) {
            const int gy = t >> 4, gx = t & 15;
            const float* base = sup_y + r * 16384 + gy * 8 * 128 + gx * 8;
            float sum = 0.f;
#pragma unroll
            for (int rr = 0; rr < 8; ++rr) {
                const float4 a = *(const float4*)(base + rr * 128);
                const float4 bb = *(const float4*)(base + rr * 128 + 4);
                sum += a.x + a.y + a.z + a.w + bb.x + bb.y + bb.z + bb.w;
            }
            const float y = sum * (1.f / 64.f);
            yv[r * 256 + t] = y;
            if (y > 0.5f) atomicOr(&flags[0], 1);
            if (y > 0.1f) atomicOr(&flags[1], 1);
        }
        __syncthreads();
        const int mode = flags[0] ? 0 : (flags[1] ? 1 : 2);
        for (int r = 0; r < 5; ++r) {
            const float y = yv[r * 256 + t];
            float mk;
            if (mode == 0)      mk = (y > 0.5f) ? 1.f : 0.f;
            else if (mode == 1) mk = (y > 0.1f) ? 1.f : 0.f;
            else                mk = 1.f;
            maskf[r * 256 + t] = mk;
        }
    }
}

// K2: per-proto mean-center + L2-normalize -> f16, pre-swizzled [m][256]
__global__ __launch_bounds__(256) void proto_fin_kernel(const float* __restrict__ cand,
                                                        _Float16* __restrict__ pro_hs) {
    const int m = blockIdx.x;
    const int t = threadIdx.x;
    const float x = cand[(size_t)m * 256 + t];
    float s1 = x, s2 = x * x;
#pragma unroll
    for (int o = 32; o >= 1; o >>= 1) {
        s1 += __shfl_xor(s1, o, 64);
        s2 += __shfl_xor(s2, o, 64);
    }
    __shared__ float r1[4], r2[4];
    __shared__ float prow[256];
    const int wv = t >> 6;
    if ((t & 63) == 0) { r1[wv] = s1; r2[wv] = s2; }
    __syncthreads();
    const float S1 = r1[0] + r1[1] + r1[2] + r1[3];
    const float S2 = r2[0] + r2[1] + r2[2] + r2[3];
    const float mu = S1 * (1.f / 256.f);
    const float nrm = sqrtf(fmaxf(S2 - 256.f * mu * mu, 0.f));
    const float inv = 1.f / fmaxf(nrm, 1e-4f);
    prow[t] = (x - mu) * inv;
    __syncthreads();
    if (t < 32) {
        const int g = t;
        f16x8 hv;
#pragma unroll
        for (int j = 0; j < 8; ++j) hv[j] = (_Float16)prow[g * 8 + j];
        *(f16x8*)(pro_hs + (size_t)m * 256 + ((g ^ (m & 7)) << 3)) = hv;
    }
}

__device__ __forceinline__ void gload_lds16h(const _Float16* g, _Float16* l) {
    __builtin_amdgcn_global_load_lds((const __attribute__((address_space(1))) unsigned int*)g,
                                     (__attribute__((address_space(3))) unsigned int*)l,
                                     16, 0, 0);
}
__device__ __forceinline__ void gload_lds16f(const float* g, float* l) {
    __builtin_amdgcn_global_load_lds((const __attribute__((address_space(1))) unsigned int*)g,
                                     (__attribute__((address_space(3))) unsigned int*)l,
                                     16, 0, 0);
}

// K3: 256 blocks x 512 thr (8 waves). Block: 64 px. Prologue: global_load_lds
// qry f32 -> qtf, normalize -> qs (f16 XOR-swizzled), hoist B-frags (qry) into
// REGISTERS (loop-invariant). Loop 20 proto-tiles of 64 m, double-buffered
// global_load_lds staging; per tile only 8 ds_read_b128 (A = protos).
// Wave w: px-half h=w&1, m 16-slice v=w>>1. Fixed-max-20 softmax accumulation.
__global__ __launch_bounds__(512, 1) void main_kernel(const float* __restrict__ qry,
                                                      const _Float16* __restrict__ pro_hs,
                                                      const float* __restrict__ maskf,
                                                      float* __restrict__ out) {
    __shared__ __align__(16) _Float16 qs[64 * 256];      // 32 KB swizzled qry f16
    __shared__ __align__(16) _Float16 ps[2][64 * 256];   // 64 KB proto dbuf (f32 qtf in prologue)
    __shared__ float red[2048];                          // 8 KB scratch / merge
    __shared__ float2 stats[64];
    __shared__ float ms[1280];                           // 5 KB masks

    const int t = threadIdx.x;
    const int w = t >> 6, l = t & 63;
    const int px0 = blockIdx.x * 64;
    float* qtf = (float*)ps;                             // [c][64px] f32 staging

    // ---- prologue: stage qry tile via global_load_lds; masks -> LDS ----
    {
        const int cb = w * 32;
#pragma unroll
        for (int i = 0; i < 8; ++i) {
            const int c = cb + i * 4;
            gload_lds16f(qry + (size_t)(c + (l >> 4)) * 16384 + px0 + (l & 15) * 4,
                         qtf + c * 64);
        }
#pragma unroll
        for (int it = 0; it < 3; ++it) {
            const int idx = it * 512 + t;
            if (idx < 1280) ms[idx] = maskf[idx];
        }
    }
    __syncthreads();   // drains vmcnt -> qtf ready
    {   // per-px partial sums over 32 channels each (bank: 2-way, free)
        const int p = t & 63, q = t >> 6;
        float s1 = 0.f, s2 = 0.f;
        for (int cc = 0; cc < 32; ++cc) {
            const float x = qtf[(q * 32 + cc) * 64 + p];
            s1 += x; s2 += x * x;
        }
        red[q * 64 + p] = s1;
        red[512 + q * 64 + p] = s2;
    }
    __syncthreads();
    if (t < 64) {
        float S1 = 0.f, S2 = 0.f;
        for (int q = 0; q < 8; ++q) { S1 += red[q * 64 + t]; S2 += red[512 + q * 64 + t]; }
        const float mu = S1 * (1.f / 256.f);
        const float nrm = sqrtf(fmaxf(S2 - 256.f * mu * mu, 0.f));
        stats[t] = make_float2(mu, 1.f / fmaxf(nrm, 1e-4f));
    }
    __syncthreads();
    {   // normalize -> qs f16 swizzled; thread = (px = t&63, eighth e = t>>6)
        const int px = t & 63, e = t >> 6;
        const float2 st = stats[px];
#pragma unroll
        for (int u = 0; u < 4; ++u) {
            const int g = e * 4 + u;
            f16x8 hv;
#pragma unroll
            for (int j = 0; j < 8; ++j)
                hv[j] = (_Float16)((qtf[(g * 8 + j) * 64 + px] - st.x) * st.y);
            *(f16x8*)(qs + px * 256 + ((g ^ (px & 7)) << 3)) = hv;
        }
    }
    __syncthreads();   // qs ready; qtf (ps) region now free for proto staging

    // ---- stage proto tile 0 (overlaps with B-frag register loads below) ----
#pragma unroll
    for (int i = 0; i < 4; ++i) {
        const int off = w * 2048 + i * 512;
        gload_lds16h(pro_hs + off + l * 8, ps[0] + off);
    }

    const int ln = l & 15, lq = l >> 4;
    const int h = w & 1, v = w >> 1;
    const int arow = v * 16 + ln;
    const int sA = arow & 7;

    // ---- hoist B (qry) fragments into registers: loop-invariant ----
    f16x8 bfr[2][8];
#pragma unroll
    for (int pxt = 0; pxt < 2; ++pxt) {
        const int px = h * 32 + pxt * 16 + ln;
        const int sB = px & 7;
#pragma unroll
        for (int ks = 0; ks < 8; ++ks) {
            const int g = ks * 4 + lq;
            bfr[pxt][ks] = *(const f16x8*)(qs + px * 256 + ((g ^ sB) << 3));
        }
    }

    float Sa[2] = {0.f, 0.f}, Wa[2] = {0.f, 0.f};

    for (int tile = 0; tile < 20; ++tile) {
        __syncthreads();                 // drains vmcnt -> ps[cur] ready
        const int cur = tile & 1;
        if (tile < 19) {                 // prefetch next tile into other buffer
            const size_t gb = (size_t)(tile + 1) * 64 * 256;
#pragma unroll
            for (int i = 0; i < 4; ++i) {
                const int off = w * 2048 + i * 512;
                gload_lds16h(pro_hs + gb + off + l * 8, ps[cur ^ 1] + off);
            }
        }
        const f32x4 mkv = *(const f32x4*)(ms + tile * 64 + v * 16 + lq * 4);
        const _Float16* pb = ps[cur];

        f32x4 acc0 = {0.f, 0.f, 0.f, 0.f}, acc1 = {0.f, 0.f, 0.f, 0.f};
#pragma unroll
        for (int ks = 0; ks < 8; ++ks) {
            const int g = ks * 4 + lq;
            const f16x8 a = *(const f16x8*)(pb + arow * 256 + ((g ^ sA) << 3));
            acc0 = __builtin_amdgcn_mfma_f32_16x16x32_f16(a, bfr[0][ks], acc0, 0, 0, 0);
            acc1 = __builtin_amdgcn_mfma_f32_16x16x32_f16(a, bfr[1][ks], acc1, 0, 0, 0);
        }

        // fixed-max epilogue: e = mk * exp(d - 20), S += e, W += e*d
#pragma unroll
        for (int pxt = 0; pxt < 2; ++pxt) {
            const f32x4 A = pxt ? acc1 : acc0;
            float ssum = 0.f, wsum = 0.f;
#pragma unroll
            for (int r = 0; r < 4; ++r) {
                const float d = 20.f * A[r];
                const float e = mkv[r] * __expf(d - 20.f);
                ssum += e; wsum += e * d;
            }
            Sa[pxt] += ssum; Wa[pxt] += wsum;
        }
    }

    __syncthreads();
#pragma unroll
    for (int pxt = 0; pxt < 2; ++pxt) {
        const int px = h * 32 + pxt * 16 + ln;
        const int slot = v * 4 + lq;
        red[px * 16 + slot] = Sa[pxt];
        red[1024 + px * 16 + slot] = Wa[pxt];
    }
    __syncthreads();
    if (t < 64) {
        float S = 0.f, W = 0.f;
        for (int s = 0; s < 16; ++s) { S += red[t * 16 + s]; W += red[1024 + t * 16 + s]; }
        out[px0 + t] = W / S;
    }
}

extern "C" void kernel_launch(void* const* d_in, const int* in_sizes, int n_in,
                              void* d_out, int out_size, void* d_ws, size_t ws_size,
                              hipStream_t stream) {
    const float* qry   = (const float*)d_in[0];   // 256*16384
    const float* sup_x = (const float*)d_in[1];   // 5*256*16384
    const float* sup_y = (const float*)d_in[2];   // 5*16384
    float* out = (float*)d_out;                   // 16384

    char* ws = (char*)d_ws;
    float*     cand   = (float*)ws;               ws += 1280 * 256 * 4;   // 1.25 MB
    float*     maskf  = (float*)ws;               ws += 1280 * 4;
    _Float16*  pro_hs = (_Float16*)ws;            /* 640 KB */

    prep_kernel<<<1281, 256, 0, stream>>>(sup_x, sup_y, cand, maskf);
    proto_fin_kernel<<<1280, 256, 0, stream>>>(cand, pro_hs);
    main_kernel<<<256, 512, 0, stream>>>(qry, pro_hs, maskf, out);
}

// Round 5
// 50.231 us; speedup vs baseline: 4.8698x; 1.0437x over previous
//
#include <hip/hip_runtime.h>
#include <math.h>

typedef _Float16 f16x8 __attribute__((ext_vector_type(8)));
typedef float f32x4 __attribute__((ext_vector_type(4)));

// ---------------------------------------------------------------------------
// Geometry: qry (256c, 16384px) f32; sup_x (5,256,16384) f32; sup_y (5,16384)
// protos M=1280, C=256, PX=16384. out (16384) f32.
// pred[px] = sum_m softmax(mask? d : NEG)_m * d_m, d = 20*<qry_n[px],pro_n[m]>
// d <= 20 -> FIXED-max softmax: e = mk*exp(d-20) in [e^-40, 1]. Masked -> 0.
// pro_h stored LINEAR [m][256] f16 (protos stream global->VGPR, no LDS).
// ---------------------------------------------------------------------------

// K1: blocks 0..1279 avg-pool one (s,c) plane of sup_x; block 1280 builds mask.
__global__ __launch_bounds__(256) void prep_kernel(const float* __restrict__ sup_x,
                                                   const float* __restrict__ sup_y,
                                                   float* __restrict__ cand,
                                                   float* __restrict__ maskf) {
    const int b = blockIdx.x;
    const int t = threadIdx.x;
    if (b < 1280) {
        __shared__ float hs[4096];       // [row 128][col4 32] horizontal 4-sums
        const int s = b >> 8, c = b & 255;
        const float4* plane = (const float4*)(sup_x + (size_t)(s * 256 + c) * 16384);
#pragma unroll
        for (int it = 0; it < 16; ++it) {     // contiguous: lanes adjacent 16B
            const float4 v = plane[it * 256 + t];
            hs[it * 256 + t] = v.x + v.y + v.z + v.w;
        }
        __syncthreads();
        const int gy = t >> 4, gx = t & 15;
        float sum = 0.f;
#pragma unroll
        for (int rr = 0; rr < 8; ++rr) {
            sum += hs[(gy * 8 + rr) * 32 + 2 * gx] + hs[(gy * 8 + rr) * 32 + 2 * gx + 1];
        }
        cand[(size_t)(s * 256 + t) * 256 + c] = sum * (1.f / 64.f);
    } else {
        __shared__ float yv[1280];
        __shared__ int flags[2];
        if (t < 2) flags[t] = 0;
        __syncthreads();
        for (int r = 0; r < 5; ++r) {
            const int gy = t >> 4, gx = t & 15;
            const float* base = sup_y + r * 16384 + gy * 8 * 128 + gx * 8;
            float sum = 0.f;
#pragma unroll
            for (int rr = 0; rr < 8; ++rr) {
                const float4 a = *(const float4*)(base + rr * 128);
                const float4 bb = *(const float4*)(base + rr * 128 + 4);
                sum += a.x + a.y + a.z + a.w + bb.x + bb.y + bb.z + bb.w;
            }
            const float y = sum * (1.f / 64.f);
            yv[r * 256 + t] = y;
            if (y > 0.5f) atomicOr(&flags[0], 1);
            if (y > 0.1f) atomicOr(&flags[1], 1);
        }
        __syncthreads();
        const int mode = flags[0] ? 0 : (flags[1] ? 1 : 2);
        for (int r = 0; r < 5; ++r) {
            const float y = yv[r * 256 + t];
            float mk;
            if (mode == 0)      mk = (y > 0.5f) ? 1.f : 0.f;
            else if (mode == 1) mk = (y > 0.1f) ? 1.f : 0.f;
            else                mk = 1.f;
            maskf[r * 256 + t] = mk;
        }
    }
}

// K2: per-proto mean-center + L2-normalize -> f16 LINEAR [m][256]
__global__ __launch_bounds__(256) void proto_fin_kernel(const float* __restrict__ cand,
                                                        _Float16* __restrict__ pro_h) {
    const int m = blockIdx.x;
    const int t = threadIdx.x;
    const float x = cand[(size_t)m * 256 + t];
    float s1 = x, s2 = x * x;
#pragma unroll
    for (int o = 32; o >= 1; o >>= 1) {
        s1 += __shfl_xor(s1, o, 64);
        s2 += __shfl_xor(s2, o, 64);
    }
    __shared__ float r1[4], r2[4];
    __shared__ float prow[256];
    const int wv = t >> 6;
    if ((t & 63) == 0) { r1[wv] = s1; r2[wv] = s2; }
    __syncthreads();
    const float S1 = r1[0] + r1[1] + r1[2] + r1[3];
    const float S2 = r2[0] + r2[1] + r2[2] + r2[3];
    const float mu = S1 * (1.f / 256.f);
    const float nrm = sqrtf(fmaxf(S2 - 256.f * mu * mu, 0.f));
    const float inv = 1.f / fmaxf(nrm, 1e-4f);
    prow[t] = (x - mu) * inv;
    __syncthreads();
    if (t < 32) {
        f16x8 hv;
#pragma unroll
        for (int j = 0; j < 8; ++j) hv[j] = (_Float16)prow[t * 8 + j];
        *(f16x8*)(pro_h + (size_t)m * 256 + t * 8) = hv;
    }
}

__device__ __forceinline__ void gload_lds16f(const float* g, float* l) {
    __builtin_amdgcn_global_load_lds((const __attribute__((address_space(1))) unsigned int*)g,
                                     (__attribute__((address_space(3))) unsigned int*)l,
                                     16, 0, 0);
}

// one 128-m tile: (optional) prefetch next A into anxt, 32 MFMA with acur,
// fixed-max softmax epilogue. All indices static after inlining.
__device__ __forceinline__ void tile_step(const _Float16* __restrict__ apn,
                                          f16x8 (&acur)[8], f16x8 (&anxt)[8],
                                          const f16x8 (&bfr)[4][8],
                                          const float* __restrict__ ms_tile, int lq,
                                          float (&Sa)[4], float (&Wa)[4]) {
    if (apn) {
#pragma unroll
        for (int ks = 0; ks < 8; ++ks) anxt[ks] = *(const f16x8*)(apn + ks * 32);
    }
    f32x4 acc[4];
#pragma unroll
    for (int p = 0; p < 4; ++p) acc[p] = (f32x4){0.f, 0.f, 0.f, 0.f};
#pragma unroll
    for (int ks = 0; ks < 8; ++ks) {
#pragma unroll
        for (int p = 0; p < 4; ++p)
            acc[p] = __builtin_amdgcn_mfma_f32_16x16x32_f16(acur[ks], bfr[p][ks], acc[p], 0, 0, 0);
    }
    const f32x4 mkv = *(const f32x4*)(ms_tile + lq * 4);
#pragma unroll
    for (int p = 0; p < 4; ++p) {
        float ssum = 0.f, wsum = 0.f;
#pragma unroll
        for (int r = 0; r < 4; ++r) {
            const float d = 20.f * acc[p][r];
            const float e = mkv[r] * __expf(d - 20.f);
            ssum += e; wsum += e * d;
        }
        Sa[p] += ssum; Wa[p] += wsum;
    }
}

// K3: 256 blocks x 512 thr (8 waves). Block: 64 px, all 1280 protos.
// Prologue: stage qry f32 -> qtf (global_load_lds), normalize -> qs f16
// (XOR-swizzled), hoist 32 B-frags/wave to regs. Main loop: 10 tiles of 128 m,
// wave w owns m-rows w*16..w*16+15 x all 64 px; A streams global->reg dbuf.
// NO barriers / NO LDS traffic in the loop.
__global__ __launch_bounds__(512, 2) void main_kernel(const float* __restrict__ qry,
                                                      const _Float16* __restrict__ pro_h,
                                                      const float* __restrict__ maskf,
                                                      float* __restrict__ out) {
    __shared__ float qtf[16384];                    // 64 KB f32 [c][64px]; reused as red
    __shared__ __align__(16) _Float16 qs[64 * 256]; // 32 KB swizzled qry f16
    __shared__ float sred[1024];                    // 4 KB partial sums
    __shared__ float ms[1280];                      // 5 KB masks
    __shared__ float2 stats[64];

    const int t = threadIdx.x;
    const int w = t >> 6, l = t & 63;
    const int ln = l & 15, lq = l >> 4;
    const int px0 = blockIdx.x * 64;
    float* red = qtf;                               // alias: qtf dead after prologue

    // ---- stage qry tile (contiguous lane-adjacent 16B) ----
#pragma unroll
    for (int i = 0; i < 8; ++i) {
        const int c = i * 32 + (t >> 4);
        gload_lds16f(qry + (size_t)c * 16384 + px0 + (t & 15) * 4,
                     qtf + i * 2048 + t * 4);
    }
    __syncthreads();   // drains vmcnt -> qtf ready
    {   // per-px partial sums (8 groups x 32 channels)
        const int p = t & 63, q = t >> 6;
        float s1 = 0.f, s2 = 0.f;
        for (int cc = 0; cc < 32; ++cc) {
            const float x = qtf[(q * 32 + cc) * 64 + p];
            s1 += x; s2 += x * x;
        }
        sred[q * 64 + p] = s1;
        sred[512 + q * 64 + p] = s2;
    }
    __syncthreads();
    if (t < 64) {
        float S1 = 0.f, S2 = 0.f;
        for (int q = 0; q < 8; ++q) { S1 += sred[q * 64 + t]; S2 += sred[512 + q * 64 + t]; }
        const float mu = S1 * (1.f / 256.f);
        const float nrm = sqrtf(fmaxf(S2 - 256.f * mu * mu, 0.f));
        stats[t] = make_float2(mu, 1.f / fmaxf(nrm, 1e-4f));
    }
    __syncthreads();
    {   // normalize -> qs f16 swizzled (chunk g at position g ^ (px&7))
        const int px = t & 63, e = t >> 6;
        const float2 st = stats[px];
#pragma unroll
        for (int u = 0; u < 4; ++u) {
            const int g = e * 4 + u;
            f16x8 hv;
#pragma unroll
            for (int j = 0; j < 8; ++j)
                hv[j] = (_Float16)((qtf[(g * 8 + j) * 64 + px] - st.x) * st.y);
            *(f16x8*)(qs + px * 256 + ((g ^ (px & 7)) << 3)) = hv;
        }
    }
    {   // masks -> LDS
#pragma unroll
        for (int it = 0; it < 3; ++it) {
            const int idx = it * 512 + t;
            if (idx < 1280) ms[idx] = maskf[idx];
        }
    }
    __syncthreads();   // qs + ms ready

    // ---- hoist B (qry) fragments: 4 px-blocks x 8 k-chunks ----
    f16x8 bfr[4][8];
#pragma unroll
    for (int p = 0; p < 4; ++p) {
        const int px = p * 16 + ln;
        const int sB = px & 7;
#pragma unroll
        for (int ks = 0; ks < 8; ++ks) {
            const int g = ks * 4 + lq;
            bfr[p][ks] = *(const f16x8*)(qs + px * 256 + ((g ^ sB) << 3));
        }
    }

    // ---- main loop: 10 tiles of 128 m, A streamed global->reg (dbuf) ----
    const _Float16* ap = pro_h + (size_t)(w * 16 + ln) * 256 + lq * 8;
    f16x8 aA[8], aB[8];
#pragma unroll
    for (int ks = 0; ks < 8; ++ks) aA[ks] = *(const f16x8*)(ap + ks * 32);

    float Sa[4] = {0.f, 0.f, 0.f, 0.f}, Wa[4] = {0.f, 0.f, 0.f, 0.f};
    const int mbase = w * 16;
#pragma unroll 1
    for (int ii = 0; ii < 5; ++ii) {
        tile_step(ap + 32768, aA, aB, bfr, ms + (2 * ii) * 128 + mbase, lq, Sa, Wa);
        tile_step(ii < 4 ? ap + 2 * 32768 : nullptr, aB, aA, bfr,
                  ms + (2 * ii + 1) * 128 + mbase, lq, Sa, Wa);
        ap += 2 * 32768;
    }

    // ---- merge: 32 (w,lq) slots per px ----
#pragma unroll
    for (int p = 0; p < 4; ++p) {
        const int px = p * 16 + ln;
        const int slot = (w * 4 + lq + px) & 31;     // rotate: conflict-free final read
        red[px * 32 + slot] = Sa[p];
        red[2048 + px * 32 + slot] = Wa[p];
    }
    __syncthreads();
    if (t < 64) {
        float S = 0.f, W = 0.f;
        for (int s = 0; s < 32; ++s) {
            const int slot = (s + t) & 31;
            S += red[t * 32 + slot];
            W += red[2048 + t * 32 + slot];
        }
        out[px0 + t] = W / S;
    }
}

extern "C" void kernel_launch(void* const* d_in, const int* in_sizes, int n_in,
                              void* d_out, int out_size, void* d_ws, size_t ws_size,
                              hipStream_t stream) {
    const float* qry   = (const float*)d_in[0];   // 256*16384
    const float* sup_x = (const float*)d_in[1];   // 5*256*16384
    const float* sup_y = (const float*)d_in[2];   // 5*16384
    float* out = (float*)d_out;                   // 16384

    char* ws = (char*)d_ws;
    float*     cand  = (float*)ws;                ws += 1280 * 256 * 4;   // 1.25 MB
    float*     maskf = (float*)ws;                ws += 1280 * 4;
    _Float16*  pro_h = (_Float16*)ws;             /* 640 KB */

    prep_kernel<<<1281, 256, 0, stream>>>(sup_x, sup_y, cand, maskf);
    proto_fin_kernel<<<1280, 256, 0, stream>>>(cand, pro_h);
    main_kernel<<<256, 512, 0, stream>>>(qry, pro_h, maskf, out);
}